// Round 1
// 287.877 us; speedup vs baseline: 1.1364x; 1.1364x over previous
//
#include <hip/hip_runtime.h>

// Problem constants
#define Dd 256           // embedding dim (== channel count C)
#define Kc 1024          // num codes
#define SPATIAL 16384    // 16*32*32
#define NROWS 65536      // 4 * SPATIAL
#define NELEM 16777216   // 4*256*16384
#define LOSS_OFF 16777216
#define IDX_OFF  16777217
#define PERP_OFF (16777217 + 65536)
#define MARGIN 3.5e-4f

typedef _Float16 f16x8 __attribute__((ext_vector_type(8)));
typedef _Float16 f16x2 __attribute__((ext_vector_type(2)));
typedef float f32x4 __attribute__((ext_vector_type(4)));

// ============================ FAST PATH =====================================

// emb -> efp (packed MFMA-B fragment layout, f16, scaled by 1024) + se.
// efp layout: [ct2=0..63][kk=0..7][lane=0..63][e=0..7] f16, where for code j,
// channel c: ct2=j>>4, l15=j&15, kk=c>>5, q=(c>>3)&3, e=c&7, lane=q*16+l15.
// A wave's B-load for (ct2,kk) is then a fully-coalesced 1KB segment.
__global__ __launch_bounds__(256) void prep2_kernel(const float* __restrict__ emb,
                                                    _Float16* __restrict__ efp,
                                                    float* __restrict__ se) {
  const int j = blockIdx.x, c = threadIdx.x;
  float v = emb[j * Dd + c];
  const int ct2 = j >> 4, l15 = j & 15;
  const int kk = c >> 5, q = (c >> 3) & 3, e = c & 7;
  efp[((size_t)(ct2 * 8 + kk) * 64 + q * 16 + l15) * 8 + e] = (_Float16)(v * 1024.0f);
  double s = (double)v * (double)v;
  #pragma unroll
  for (int off = 32; off; off >>= 1) s += __shfl_down(s, off, 64);
  __shared__ double ws4[4];
  if ((threadIdx.x & 63) == 0) ws4[threadIdx.x >> 6] = s;
  __syncthreads();
  if (threadIdx.x == 0) se[j] = (float)(ws4[0] + ws4[1] + ws4[2] + ws4[3]);
}

// Fused: z-tile transpose->f16 (LDS) + sx (f64) + MFMA scores in registers +
// per-row min + margin flagging. 32 rows x 1024 cols per block; 8 waves, wave
// w owns cols [w*128, w*128+128). Scores packed f16x2 in 32 VGPRs/thread.
// 512 threads + VGPR cap 128 (launch_bounds(512,4)) -> 2 blocks (16 waves)/CU.
__global__ __launch_bounds__(512, 4) void prefilter2_kernel(const float* __restrict__ z,
                                                            const _Float16* __restrict__ efp,
                                                            const float* __restrict__ se,
                                                            float* __restrict__ sx,
                                                            float* __restrict__ rowmin,
                                                            int* __restrict__ candcount,
                                                            int* __restrict__ cand_g) {
  __shared__ _Float16 As[32 * 272];    // 17408 B transposed z tile
  __shared__ double sxp[16][32];
  __shared__ float selds[Kc];
  __shared__ int cnts[32];
  __shared__ int cands[32][8];
  __shared__ float rminw[8][32];
  __shared__ float rthr[32];

  const int tid = threadIdx.x;
  const int n0 = blockIdx.x * 32;
  const int b = n0 >> 14, s0 = n0 & 16383;
  const float* zb = z + (size_t)b * (Dd * SPATIAL) + s0;

  // stage + transpose + sx partials (512 threads: 16 channels each)
  {
    const int r = tid & 31, cp = tid >> 5;   // cp in 0..15
    double acc = 0.0;
    #pragma unroll
    for (int c = cp * 16; c < cp * 16 + 16; ++c) {
      const float v = zb[(size_t)c * SPATIAL + r];
      As[r * 272 + c] = (_Float16)v;
      acc += (double)v * (double)v;
    }
    sxp[cp][r] = acc;
  }
  selds[tid] = se[tid];
  selds[tid + 512] = se[tid + 512];
  if (tid < 32) cnts[tid] = 0;
  __syncthreads();
  if (tid < 32) {
    double s = 0.0;
    #pragma unroll
    for (int p = 0; p < 16; ++p) s += sxp[p][tid];
    sx[n0 + tid] = (float)s;
  }

  const int w = tid >> 6, lane = tid & 63, q = lane >> 4, l15 = lane & 15;
  const int colbase = w * 128;

  // A fragments -> registers (rows rt*16+l15, k = kk*32 + q*8)
  f16x8 Afrag[2][8];
  #pragma unroll
  for (int rt = 0; rt < 2; ++rt)
    #pragma unroll
    for (int kk = 0; kk < 8; ++kk)
      Afrag[rt][kk] = *(const f16x8*)(&As[(rt * 16 + l15) * 272 + kk * 32 + q * 8]);

  float rmin8[8];
  #pragma unroll
  for (int i = 0; i < 8; ++i) rmin8[i] = 3.4e38f;
  f16x2 scst[8][4];

  #pragma unroll
  for (int ct = 0; ct < 8; ++ct) {
    // coalesced packed-B: 1KB contiguous per (ct,kk) across the wave
    const _Float16* bp = efp + ((size_t)((w * 8 + ct) * 8) * 64 + lane) * 8;
    f32x4 a0 = {0.f, 0.f, 0.f, 0.f}, a1 = {0.f, 0.f, 0.f, 0.f};
    #pragma unroll
    for (int kk = 0; kk < 8; ++kk) {
      const f16x8 B = *(const f16x8*)(bp + kk * 512);
      a0 = __builtin_amdgcn_mfma_f32_16x16x32_f16(Afrag[0][kk], B, a0, 0, 0, 0);
      a1 = __builtin_amdgcn_mfma_f32_16x16x32_f16(Afrag[1][kk], B, a1, 0, 0, 0);
    }
    const float sec = selds[colbase + ct * 16 + l15];
    #pragma unroll
    for (int reg = 0; reg < 4; ++reg) {
      const float sc0 = fmaf(-0.001953125f, a0[reg], sec);  // se - 2P (/1024 scale)
      const float sc1 = fmaf(-0.001953125f, a1[reg], sec);
      rmin8[reg]     = fminf(rmin8[reg], sc0);
      rmin8[reg + 4] = fminf(rmin8[reg + 4], sc1);
      scst[ct][reg] = (f16x2){(_Float16)sc0, (_Float16)sc1};
    }
  }

  // cross-lane row-min (lanes sharing q hold same rows)
  #pragma unroll
  for (int m = 1; m <= 8; m <<= 1)
    #pragma unroll
    for (int i = 0; i < 8; ++i) rmin8[i] = fminf(rmin8[i], __shfl_xor(rmin8[i], m, 64));
  if (l15 == 0) {
    #pragma unroll
    for (int reg = 0; reg < 4; ++reg) {
      rminw[w][q * 4 + reg] = rmin8[reg];
      rminw[w][16 + q * 4 + reg] = rmin8[4 + reg];
    }
  }
  __syncthreads();
  if (tid < 32) {
    float m = rminw[0][tid];
    #pragma unroll
    for (int ww = 1; ww < 8; ++ww) m = fminf(m, rminw[ww][tid]);
    rowmin[n0 + tid] = m;
    rthr[tid] = m + MARGIN;
  }
  __syncthreads();

  // flag pass over register scores
  float thr0[4], thr1[4];
  #pragma unroll
  for (int reg = 0; reg < 4; ++reg) {
    thr0[reg] = rthr[q * 4 + reg];
    thr1[reg] = rthr[16 + q * 4 + reg];
  }
  #pragma unroll
  for (int ct = 0; ct < 8; ++ct) {
    const int col = colbase + ct * 16 + l15;
    #pragma unroll
    for (int reg = 0; reg < 4; ++reg) {
      if ((float)scst[ct][reg][0] < thr0[reg]) {
        const int pos = atomicAdd(&cnts[q * 4 + reg], 1);
        if (pos < 8) cands[q * 4 + reg][pos] = col;
      }
      if ((float)scst[ct][reg][1] < thr1[reg]) {
        const int pos = atomicAdd(&cnts[16 + q * 4 + reg], 1);
        if (pos < 8) cands[16 + q * 4 + reg][pos] = col;
      }
    }
  }
  __syncthreads();
  if (tid < 32) candcount[n0 + tid] = cnts[tid];   // >8 => full-rescore marker
  if (tid < 256)
    cand_g[(size_t)(n0 + (tid >> 3)) * 8 + (tid & 7)] = cands[tid >> 3][tid & 7];
}

// cnt==1 rows resolved directly (+loss partial); others appended to hard list
__global__ __launch_bounds__(256) void resolve_easy_kernel(const int* __restrict__ candcount,
                                                           const int* __restrict__ cand_g,
                                                           const float* __restrict__ sx,
                                                           const float* __restrict__ rowmin,
                                                           float* __restrict__ out_idx_f,
                                                           int* __restrict__ idx_i,
                                                           int* __restrict__ counts,
                                                           int* __restrict__ hardcnt,
                                                           int* __restrict__ hardlist,
                                                           double* __restrict__ loss_sum) {
  const int tid = threadIdx.x;
  const int n = blockIdx.x * 256 + tid;
  const int cnt = candcount[n];
  double lp = 0.0;
  if (cnt == 1) {
    const int j = cand_g[(size_t)n * 8];
    idx_i[n] = j;
    out_idx_f[n] = (float)j;
    atomicAdd(&counts[j], 1);
    lp = (double)sx[n] + (double)rowmin[n];   // ||z-e||^2 = sx + (se - 2P)
  } else {
    const int pos = atomicAdd(hardcnt, 1);
    hardlist[pos] = n;
  }
  #pragma unroll
  for (int off = 32; off; off >>= 1) lp += __shfl_down(lp, off, 64);
  __shared__ double dred[4];
  if ((tid & 63) == 0) dred[tid >> 6] = lp;
  __syncthreads();
  if (tid == 0) atomicAdd(loss_sum, dred[0] + dred[1] + dred[2] + dred[3]);
}

// exact reference-rounded rescore of hard rows; cnt<=8 lane-parallel cands,
// cnt>8 full 1024-code scan. Also accumulates loss for these rows.
__global__ __launch_bounds__(256) void resolve_hard_kernel(const float* __restrict__ z,
                                                           const float* __restrict__ emb,
                                                           const float* __restrict__ se,
                                                           const float* __restrict__ sx,
                                                           const int* __restrict__ candcount,
                                                           const int* __restrict__ cand_g,
                                                           const int* __restrict__ hardcnt,
                                                           const int* __restrict__ hardlist,
                                                           float* __restrict__ out_idx_f,
                                                           int* __restrict__ idx_i,
                                                           int* __restrict__ counts,
                                                           double* __restrict__ loss_sum) {
  __shared__ float xs[4][256];
  const int tid = threadIdx.x, w = tid >> 6, lane = tid & 63;
  const int hc = *hardcnt;
  const int nw = gridDim.x * 4;
  double wloss = 0.0;
  for (int i = blockIdx.x * 4 + w; i < hc; i += nw) {
    const int n = hardlist[i];
    const int b = n >> 14, s = n & 16383;
    #pragma unroll
    for (int ro = 0; ro < 4; ++ro)
      xs[w][ro * 64 + lane] =
          z[(size_t)b * (Dd * SPATIAL) + (size_t)(ro * 64 + lane) * SPATIAL + s];
    asm volatile("s_waitcnt lgkmcnt(0) vmcnt(0)" ::: "memory");
    const int cnt = candcount[n];
    const float sxn = sx[n];
    float scb = 3.4e38f;
    int jb = 0x7fffffff;
    if (cnt <= 8) {
      if (lane < cnt) {
        jb = cand_g[(size_t)n * 8 + lane];
        const float4* ep = (const float4*)(emb + (size_t)jb * Dd);
        float acc = 0.f;
        #pragma unroll 8
        for (int kk = 0; kk < 64; ++kk) {
          const float4 e4 = ep[kk];
          const float* xp = &xs[w][kk * 4];
          acc = fmaf(xp[0], e4.x, acc);
          acc = fmaf(xp[1], e4.y, acc);
          acc = fmaf(xp[2], e4.z, acc);
          acc = fmaf(xp[3], e4.w, acc);
        }
        const float t1 = sxn + se[jb];
        scb = t1 - 2.0f * acc;
      }
    } else {
      // full exact scan: 16 codes per lane, ascending j per lane
      for (int jj = 0; jj < 16; ++jj) {
        const int j = lane * 16 + jj;
        const float4* ep = (const float4*)(emb + (size_t)j * Dd);
        float acc = 0.f;
        #pragma unroll 8
        for (int kk = 0; kk < 64; ++kk) {
          const float4 e4 = ep[kk];
          const float* xp = &xs[w][kk * 4];
          acc = fmaf(xp[0], e4.x, acc);
          acc = fmaf(xp[1], e4.y, acc);
          acc = fmaf(xp[2], e4.z, acc);
          acc = fmaf(xp[3], e4.w, acc);
        }
        const float t1 = sxn + se[j];
        const float sc = t1 - 2.0f * acc;
        if (sc < scb) { scb = sc; jb = j; }   // ascending j => strict < keeps first
      }
    }
    #pragma unroll
    for (int m = 1; m <= 32; m <<= 1) {
      const float so = __shfl_xor(scb, m, 64);
      const int jo = __shfl_xor(jb, m, 64);
      if (so < scb || (so == scb && jo < jb)) { scb = so; jb = jo; }
    }
    if (lane == 0) {
      idx_i[n] = jb;
      out_idx_f[n] = (float)jb;
      atomicAdd(&counts[jb], 1);
      wloss += (double)sxn + (double)scb;
    }
  }
  if (lane == 0) atomicAdd(loss_sum, wloss);
}

// gather-only z_q write (out == z_q; straight-through is identity in fwd)
__global__ __launch_bounds__(256) void phase2c_kernel(const float* __restrict__ emb,
                                                      const int* __restrict__ idx_i,
                                                      float* __restrict__ out_zq) {
  __shared__ float els[64 * 257];
  __shared__ int sidx[64];
  const int tid = threadIdx.x;
  const int blk = blockIdx.x, b = blk >> 8, s0 = (blk & 255) << 6;
  if (tid < 64) sidx[tid] = idx_i[b * SPATIAL + s0 + tid];
  __syncthreads();
  {
    const int rr = tid >> 2, p = tid & 3;
    const float* ep = emb + (size_t)sidx[rr] * Dd + p * 64;
    float* dl = els + rr * 257 + p * 64;
    #pragma unroll
    for (int i = 0; i < 64; i += 4) {
      const float4 e4 = *(const float4*)(ep + i);
      dl[i] = e4.x; dl[i + 1] = e4.y; dl[i + 2] = e4.z; dl[i + 3] = e4.w;
    }
  }
  __syncthreads();
  // vectorized store-out: lane covers 4 spatial positions -> float4 stores
  const int s4 = tid & 15, cg = tid >> 4;
  const size_t zb = (size_t)b * (Dd * SPATIAL);
  #pragma unroll 4
  for (int c = cg; c < Dd; c += 16) {
    float4 v;
    v.x = els[(s4 * 4 + 0) * 257 + c];
    v.y = els[(s4 * 4 + 1) * 257 + c];
    v.z = els[(s4 * 4 + 2) * 257 + c];
    v.w = els[(s4 * 4 + 3) * 257 + c];
    *(float4*)(out_zq + zb + (size_t)c * SPATIAL + s0 + s4 * 4) = v;
  }
}

__global__ __launch_bounds__(256) void finalize_kernel(const int* __restrict__ counts,
                                                       const double* __restrict__ loss_sum,
                                                       float* __restrict__ out) {
  const int tid = threadIdx.x;
  double local = 0.0;
  for (int k = tid; k < Kc; k += 256) {
    const double p = (double)counts[k] / (double)NROWS;
    local += p * log(p + 1e-10);
  }
  #pragma unroll
  for (int off = 32; off; off >>= 1) local += __shfl_down(local, off, 64);
  __shared__ double dred[4];
  if ((tid & 63) == 0) dred[tid >> 6] = local;
  __syncthreads();
  if (tid == 0) {
    const double H = dred[0] + dred[1] + dred[2] + dred[3];
    out[PERP_OFF] = (float)exp(-H);
    out[LOSS_OFF] = (float)(0.25 * loss_sum[0] / (double)NELEM);
  }
}

// ===================== OLD (round-3) FALLBACK PATH ==========================

__global__ __launch_bounds__(256) void prep_kernel(const float* __restrict__ emb,
                                                   float* __restrict__ eT,
                                                   float* __restrict__ se) {
  const int j = blockIdx.x, c = threadIdx.x;
  float v = emb[j * Dd + c];
  eT[c * Kc + j] = v;
  double s = (double)v * (double)v;
  #pragma unroll
  for (int off = 32; off; off >>= 1) s += __shfl_down(s, off, 64);
  __shared__ double ws4[4];
  if ((threadIdx.x & 63) == 0) ws4[threadIdx.x >> 6] = s;
  __syncthreads();
  if (threadIdx.x == 0) se[j] = (float)(ws4[0] + ws4[1] + ws4[2] + ws4[3]);
}

__global__ __launch_bounds__(256) void sx_kernel(const float* __restrict__ z,
                                                 float* __restrict__ sx) {
  __shared__ double part[4][64];
  const int tid = threadIdx.x, r = tid & 63, cg = tid >> 6;
  const int blk = blockIdx.x, b = blk >> 8, s0 = (blk & 255) << 6;
  const float* zb = z + (size_t)b * (Dd * SPATIAL);
  double acc = 0.0;
  for (int c = cg * 64; c < cg * 64 + 64; ++c) {
    const float v = zb[(size_t)c * SPATIAL + s0 + r];
    acc += (double)v * (double)v;
  }
  part[cg][r] = acc;
  __syncthreads();
  if (tid < 64)
    sx[b * SPATIAL + s0 + tid] =
        (float)(part[0][tid] + part[1][tid] + part[2][tid] + part[3][tid]);
}

__global__ __launch_bounds__(256) void argmin_kernel(const float* __restrict__ z,
                                                     const float* __restrict__ eT,
                                                     const float* __restrict__ se,
                                                     const float* __restrict__ sx,
                                                     float* __restrict__ out_idx_f,
                                                     int* __restrict__ idx_i,
                                                     int* __restrict__ counts) {
  __shared__ float As[32 * 64];
  __shared__ float Bs[32 * 64];
  __shared__ float ses[Kc];
  __shared__ float sxs[64];
  __shared__ float redS1[64 * 16];
  __shared__ int   redI1[64 * 16];
  const int tid = threadIdx.x, tc = tid & 15, tr = tid >> 4;
  const int blk = blockIdx.x, b = blk >> 8, s0 = (blk & 255) << 6;
  const float* zb = z + (size_t)b * (Dd * SPATIAL);
  #pragma unroll
  for (int i = 0; i < 4; ++i) ses[tid + 256 * i] = se[tid + 256 * i];
  if (tid < 64) sxs[tid] = sx[b * SPATIAL + s0 + tid];
  float s1[4]; int j1[4];
  #pragma unroll
  for (int r = 0; r < 4; ++r) { s1[r] = 3.4e38f; j1[r] = 0; }
  for (int j0 = 0; j0 < Kc; j0 += 64) {
    float acc[4][4];
    #pragma unroll
    for (int rr = 0; rr < 4; ++rr)
      #pragma unroll
      for (int cc = 0; cc < 4; ++cc) acc[rr][cc] = 0.0f;
    for (int c0 = 0; c0 < Dd; c0 += 32) {
      __syncthreads();
      #pragma unroll
      for (int i = 0; i < 8; ++i) {
        const int e = i * 256 + tid, ci = e >> 6, r = e & 63;
        As[e] = zb[(size_t)(c0 + ci) * SPATIAL + s0 + r];
        Bs[e] = eT[(c0 + ci) * Kc + j0 + r];
      }
      __syncthreads();
      #pragma unroll
      for (int d = 0; d < 32; ++d) {
        const float4 av = *reinterpret_cast<const float4*>(&As[d * 64 + 4 * tr]);
        const float4 bv = *reinterpret_cast<const float4*>(&Bs[d * 64 + 4 * tc]);
        const float aa[4] = {av.x, av.y, av.z, av.w};
        const float bb[4] = {bv.x, bv.y, bv.z, bv.w};
        #pragma unroll
        for (int rr = 0; rr < 4; ++rr)
          #pragma unroll
          for (int cc = 0; cc < 4; ++cc)
            acc[rr][cc] = fmaf(aa[rr], bb[cc], acc[rr][cc]);
      }
    }
    #pragma unroll
    for (int rr = 0; rr < 4; ++rr) {
      const float sxr = sxs[4 * tr + rr];
      #pragma unroll
      for (int cc = 0; cc < 4; ++cc) {
        const int j = j0 + 4 * tc + cc;
        const float t1 = sxr + ses[j];
        const float s = t1 - 2.0f * acc[rr][cc];
        if (s < s1[rr] || (s == s1[rr] && j < j1[rr])) { s1[rr] = s; j1[rr] = j; }
      }
    }
  }
  #pragma unroll
  for (int rr = 0; rr < 4; ++rr) {
    redS1[(4 * tr + rr) * 16 + tc] = s1[rr];
    redI1[(4 * tr + rr) * 16 + tc] = j1[rr];
  }
  __syncthreads();
  if (tid < 64) {
    float bs = redS1[tid * 16];
    int bj = redI1[tid * 16];
    #pragma unroll
    for (int t = 1; t < 16; ++t) {
      const float a1 = redS1[tid * 16 + t];
      const int aj = redI1[tid * 16 + t];
      if (a1 < bs || (a1 == bs && aj < bj)) { bs = a1; bj = aj; }
    }
    const int n = b * SPATIAL + s0 + tid;
    out_idx_f[n] = (float)bj;
    idx_i[n] = bj;
    atomicAdd(&counts[bj], 1);
  }
}

__global__ __launch_bounds__(256) void phase2_kernel(const float* __restrict__ z,
                                                     const float* __restrict__ eT,
                                                     const int* __restrict__ idx_i,
                                                     float* __restrict__ out_zq,
                                                     double* __restrict__ loss_sum) {
  __shared__ int sidx[64];
  __shared__ double dred[4];
  const int tid = threadIdx.x;
  const int blk = blockIdx.x, b = blk >> 8, s0 = (blk & 255) << 6;
  if (tid < 64) sidx[tid] = idx_i[b * SPATIAL + s0 + tid];
  __syncthreads();
  const int s = tid & 63, coff = tid >> 6;
  const size_t zb = (size_t)b * (Dd * SPATIAL);
  const int myidx = sidx[s];
  double lsum = 0.0;
  for (int c = coff; c < Dd; c += 4) {
    const size_t off = zb + (size_t)c * SPATIAL + s0 + s;
    const float zv = z[off];
    const float zq = eT[c * Kc + myidx];
    out_zq[off] = zv + (zq - zv);
    const float d = zv - zq;
    lsum += (double)d * (double)d;
  }
  #pragma unroll
  for (int off = 32; off; off >>= 1) lsum += __shfl_down(lsum, off, 64);
  if ((tid & 63) == 0) dred[tid >> 6] = lsum;
  __syncthreads();
  if (tid == 0) atomicAdd(loss_sum, dred[0] + dred[1] + dred[2] + dred[3]);
}

// ================================ LAUNCH ====================================

extern "C" void kernel_launch(void* const* d_in, const int* in_sizes, int n_in,
                              void* d_out, int out_size, void* d_ws, size_t ws_size,
                              hipStream_t stream) {
  const float* z   = (const float*)d_in[0];
  const float* emb = (const float*)d_in[1];
  float* out = (float*)d_out;
  char* ws = (char*)d_ws;

  // fast-path ws layout
  const size_t OFF_SE   = 8192;
  const size_t OFF_SX   = 12288;
  const size_t OFF_EF   = 274432;
  const size_t OFF_RM   = 798720;
  const size_t OFF_IDX  = 1060864;
  const size_t OFF_CCT  = 1323008;
  const size_t OFF_CAND = 1585152;
  const size_t OFF_HARD = 3682304;
  const size_t NEED     = 3944448;

  double* loss_sum = (double*)(ws + 0);
  int*    hardcnt  = (int*)(ws + 8);
  int*    counts   = (int*)(ws + 256);

  hipMemsetAsync(d_ws, 0, 8192, stream);  // loss_sum + hardcnt + counts

  if (ws_size >= NEED) {
    float*    se        = (float*)(ws + OFF_SE);
    float*    sx        = (float*)(ws + OFF_SX);
    _Float16* efp       = (_Float16*)(ws + OFF_EF);
    float*    rowmin    = (float*)(ws + OFF_RM);
    int*      idx_i     = (int*)(ws + OFF_IDX);
    int*      candcount = (int*)(ws + OFF_CCT);
    int*      cand_g    = (int*)(ws + OFF_CAND);
    int*      hardlist  = (int*)(ws + OFF_HARD);

    prep2_kernel<<<Kc, 256, 0, stream>>>(emb, efp, se);
    prefilter2_kernel<<<2048, 512, 0, stream>>>(z, efp, se, sx, rowmin,
                                                candcount, cand_g);
    resolve_easy_kernel<<<256, 256, 0, stream>>>(candcount, cand_g, sx, rowmin,
                                                 out + IDX_OFF, idx_i, counts,
                                                 hardcnt, hardlist, loss_sum);
    resolve_hard_kernel<<<256, 256, 0, stream>>>(z, emb, se, sx, candcount, cand_g,
                                                 hardcnt, hardlist, out + IDX_OFF,
                                                 idx_i, counts, loss_sum);
    phase2c_kernel<<<1024, 256, 0, stream>>>(emb, idx_i, out);
    finalize_kernel<<<1, 256, 0, stream>>>(counts, loss_sum, out);
  } else {
    // round-3 proven fallback
    float* eT    = (float*)(ws + 8192);
    float* se    = (float*)(ws + 8192 + 1048576);
    float* sx    = (float*)(ws + 8192 + 1048576 + 4096);
    int*   idx_i = (int*)(ws + 8192 + 1048576 + 4096 + 262144);

    prep_kernel<<<Kc, 256, 0, stream>>>(emb, eT, se);
    sx_kernel<<<1024, 256, 0, stream>>>(z, sx);
    argmin_kernel<<<1024, 256, 0, stream>>>(z, eT, se, sx, out + IDX_OFF, idx_i, counts);
    phase2_kernel<<<1024, 256, 0, stream>>>(z, eT, idx_i, out, loss_sum);
    finalize_kernel<<<1, 256, 0, stream>>>(counts, loss_sum, out);
  }
}

// Round 2
// 262.873 us; speedup vs baseline: 1.2444x; 1.0951x over previous
//
#include <hip/hip_runtime.h>

// Problem constants
#define Dd 256           // embedding dim (== channel count C)
#define Kc 1024          // num codes
#define SPATIAL 16384    // 16*32*32
#define NROWS 65536      // 4 * SPATIAL
#define NELEM 16777216   // 4*256*16384
#define LOSS_OFF 16777216
#define IDX_OFF  16777217
#define PERP_OFF (16777217 + 65536)
#define MARGIN 3.5e-4f
#define SCSTRIDE 1048    // f16 elems; 2096B row stride (16B aligned, dw%32==12)

typedef _Float16 f16x8 __attribute__((ext_vector_type(8)));
typedef float f32x4 __attribute__((ext_vector_type(4)));

// ============================ FAST PATH =====================================

// emb -> efp (packed MFMA-B fragment layout, f16, scaled by 1024) + se.
// efp layout: [ct2=0..63][kk=0..7][lane=0..63][e=0..7] f16, where for code j,
// channel c: ct2=j>>4, l15=j&15, kk=c>>5, q=(c>>3)&3, e=c&7, lane=q*16+l15.
__global__ __launch_bounds__(256) void prep2_kernel(const float* __restrict__ emb,
                                                    _Float16* __restrict__ efp,
                                                    float* __restrict__ se) {
  const int j = blockIdx.x, c = threadIdx.x;
  float v = emb[j * Dd + c];
  const int ct2 = j >> 4, l15 = j & 15;
  const int kk = c >> 5, q = (c >> 3) & 3, e = c & 7;
  efp[((size_t)(ct2 * 8 + kk) * 64 + q * 16 + l15) * 8 + e] = (_Float16)(v * 1024.0f);
  double s = (double)v * (double)v;
  #pragma unroll
  for (int off = 32; off; off >>= 1) s += __shfl_down(s, off, 64);
  __shared__ double ws4[4];
  if ((threadIdx.x & 63) == 0) ws4[threadIdx.x >> 6] = s;
  __syncthreads();
  if (threadIdx.x == 0) se[j] = (float)(ws4[0] + ws4[1] + ws4[2] + ws4[3]);
}

// Fused: z transpose->f16 + sx + MFMA scores -> LDS (union with stage tile;
// no register score array -> no scratch spill) + row-min + margin flagging +
// inline easy-row resolve (idx/counts/loss) + ordered hard-list append.
// 32 rows x 1024 cols per block; 8 waves; wave w owns cols [w*128, w*128+128).
__global__ __launch_bounds__(512, 4) void prefilter2_kernel(const float* __restrict__ z,
                                                            const _Float16* __restrict__ efp,
                                                            const float* __restrict__ se,
                                                            float* __restrict__ sx,
                                                            int* __restrict__ candcount,
                                                            int* __restrict__ cand_g,
                                                            float* __restrict__ out_idx_f,
                                                            int* __restrict__ idx_i,
                                                            int* __restrict__ counts,
                                                            int* __restrict__ hardcnt,
                                                            int* __restrict__ hardlist,
                                                            double* __restrict__ loss_sum) {
  // union: stage tile As[32][272] (17.4KB) then score buffer [32][SCSTRIDE] (67KB)
  __shared__ __align__(16) _Float16 scAs[32 * SCSTRIDE];
  __shared__ double sxp[16][32];
  __shared__ float selds[Kc];
  __shared__ int cnts[32];
  __shared__ int cands[32][8];
  __shared__ float rminw[8][32];
  __shared__ float rthr[32];

  const int tid = threadIdx.x;
  const int n0 = blockIdx.x * 32;
  const int b = n0 >> 14, s0 = n0 & 16383;
  const float* zb = z + (size_t)b * (Dd * SPATIAL) + s0;

  // stage + transpose + sx partials (512 threads: 16 channels each)
  {
    const int r = tid & 31, cp = tid >> 5;   // cp in 0..15
    double acc = 0.0;
    #pragma unroll
    for (int c = cp * 16; c < cp * 16 + 16; ++c) {
      const float v = zb[(size_t)c * SPATIAL + r];
      scAs[r * 272 + c] = (_Float16)v;
      acc += (double)v * (double)v;
    }
    sxp[cp][r] = acc;
  }
  selds[tid] = se[tid];
  selds[tid + 512] = se[tid + 512];
  if (tid < 32) cnts[tid] = 0;
  __syncthreads();

  float sxv = 0.0f;            // per-row ||z||^2 (rows tid<32)
  if (tid < 32) {
    double s = 0.0;
    #pragma unroll
    for (int p = 0; p < 16; ++p) s += sxp[p][tid];
    sxv = (float)s;
    sx[n0 + tid] = sxv;
  }

  const int w = tid >> 6, lane = tid & 63, q = lane >> 4, l15 = lane & 15;
  const int colbase = w * 128;

  // A fragments -> registers (rows rt*16+l15, k = kk*32 + q*8)
  f16x8 Afrag[2][8];
  #pragma unroll
  for (int rt = 0; rt < 2; ++rt)
    #pragma unroll
    for (int kk = 0; kk < 8; ++kk)
      Afrag[rt][kk] = *(const f16x8*)(&scAs[(rt * 16 + l15) * 272 + kk * 32 + q * 8]);

  __syncthreads();   // stage tile dead; region becomes the score buffer

  float rmin8[8];
  #pragma unroll
  for (int i = 0; i < 8; ++i) rmin8[i] = 3.4e38f;

  #pragma unroll
  for (int ct = 0; ct < 8; ++ct) {
    // coalesced packed-B: 1KB contiguous per (ct,kk) across the wave
    const _Float16* bp = efp + ((size_t)((w * 8 + ct) * 8) * 64 + lane) * 8;
    f32x4 a0 = {0.f, 0.f, 0.f, 0.f}, a1 = {0.f, 0.f, 0.f, 0.f};
    #pragma unroll
    for (int kk = 0; kk < 8; ++kk) {
      const f16x8 B = *(const f16x8*)(bp + kk * 512);
      a0 = __builtin_amdgcn_mfma_f32_16x16x32_f16(Afrag[0][kk], B, a0, 0, 0, 0);
      a1 = __builtin_amdgcn_mfma_f32_16x16x32_f16(Afrag[1][kk], B, a1, 0, 0, 0);
    }
    const int col = colbase + ct * 16 + l15;
    const float sec = selds[col];
    #pragma unroll
    for (int reg = 0; reg < 4; ++reg) {
      const float sc0 = fmaf(-0.001953125f, a0[reg], sec);  // se - 2P (/1024 scale)
      const float sc1 = fmaf(-0.001953125f, a1[reg], sec);
      rmin8[reg]     = fminf(rmin8[reg], sc0);
      rmin8[reg + 4] = fminf(rmin8[reg + 4], sc1);
      scAs[(q * 4 + reg) * SCSTRIDE + col]      = (_Float16)sc0;
      scAs[(16 + q * 4 + reg) * SCSTRIDE + col] = (_Float16)sc1;
    }
  }

  // cross-lane row-min (lanes sharing q hold same rows)
  #pragma unroll
  for (int m = 1; m <= 8; m <<= 1)
    #pragma unroll
    for (int i = 0; i < 8; ++i) rmin8[i] = fminf(rmin8[i], __shfl_xor(rmin8[i], m, 64));
  if (l15 == 0) {
    #pragma unroll
    for (int reg = 0; reg < 4; ++reg) {
      rminw[w][q * 4 + reg] = rmin8[reg];
      rminw[w][16 + q * 4 + reg] = rmin8[4 + reg];
    }
  }
  __syncthreads();   // also publishes all score ds_writes

  float rm1 = 0.0f;            // per-row global min (rows tid<32)
  if (tid < 32) {
    float m = rminw[0][tid];
    #pragma unroll
    for (int ww = 1; ww < 8; ++ww) m = fminf(m, rminw[ww][tid]);
    rm1 = m;
    rthr[tid] = m + MARGIN;
  }
  __syncthreads();

  // flag pass: vector readback of LDS scores; thread = (row, 16-col slice)
  {
    const int row = tid >> 4, t4 = tid & 15;
    const float thr = rthr[row];
    #pragma unroll
    for (int i = 0; i < 8; ++i) {
      const f16x8 v = *(const f16x8*)(&scAs[row * SCSTRIDE + t4 * 8 + i * 128]);
      #pragma unroll
      for (int e = 0; e < 8; ++e) {
        if ((float)v[e] < thr) {
          const int pos = atomicAdd(&cnts[row], 1);
          if (pos < 8) cands[row][pos] = t4 * 8 + i * 128 + e;
        }
      }
    }
  }
  __syncthreads();

  // epilogue: easy rows resolved inline; hard rows appended in block order
  if (tid < 256)
    cand_g[(size_t)(n0 + (tid >> 3)) * 8 + (tid & 7)] = cands[tid >> 3][tid & 7];
  if (tid < 64) {
    double lp = 0.0;
    int hard = 0;
    const int n = n0 + tid;
    if (tid < 32) {
      const int cnt = cnts[tid];
      candcount[n] = cnt;
      if (cnt == 1) {
        const int j = cands[tid][0];
        idx_i[n] = j;
        out_idx_f[n] = (float)j;
        atomicAdd(&counts[j], 1);
        lp = (double)sxv + (double)rm1;   // ||z-e||^2 = sx + (se - 2P)
      } else {
        hard = 1;
      }
    }
    const unsigned long long mask = __ballot(hard);
    const int h = __popcll(mask);
    int base = 0;
    if (tid == 0 && h) base = atomicAdd(hardcnt, h);
    base = __shfl(base, 0, 64);
    if (hard) {
      const int rank = __popcll(mask & ((1ull << tid) - 1ull));
      hardlist[base + rank] = n;
    }
    #pragma unroll
    for (int off = 32; off; off >>= 1) lp += __shfl_down(lp, off, 64);
    if (tid == 0 && lp != 0.0) atomicAdd(loss_sum, lp);
  }
}

// exact reference-rounded rescore of hard rows; cnt<=8 lane-parallel cands,
// cnt>8 full 1024-code scan. Also accumulates loss for these rows.
__global__ __launch_bounds__(256) void resolve_hard_kernel(const float* __restrict__ z,
                                                           const float* __restrict__ emb,
                                                           const float* __restrict__ se,
                                                           const float* __restrict__ sx,
                                                           const int* __restrict__ candcount,
                                                           const int* __restrict__ cand_g,
                                                           const int* __restrict__ hardcnt,
                                                           const int* __restrict__ hardlist,
                                                           float* __restrict__ out_idx_f,
                                                           int* __restrict__ idx_i,
                                                           int* __restrict__ counts,
                                                           double* __restrict__ loss_sum) {
  __shared__ float xs[4][256];
  const int tid = threadIdx.x, w = tid >> 6, lane = tid & 63;
  const int hc = *hardcnt;
  const int nw = gridDim.x * 4;
  double wloss = 0.0;
  for (int i = blockIdx.x * 4 + w; i < hc; i += nw) {
    const int n = hardlist[i];
    const int b = n >> 14, s = n & 16383;
    #pragma unroll
    for (int ro = 0; ro < 4; ++ro)
      xs[w][ro * 64 + lane] =
          z[(size_t)b * (Dd * SPATIAL) + (size_t)(ro * 64 + lane) * SPATIAL + s];
    asm volatile("s_waitcnt lgkmcnt(0) vmcnt(0)" ::: "memory");
    const int cnt = candcount[n];
    const float sxn = sx[n];
    float scb = 3.4e38f;
    int jb = 0x7fffffff;
    if (cnt <= 8) {
      if (lane < cnt) {
        jb = cand_g[(size_t)n * 8 + lane];
        const float4* ep = (const float4*)(emb + (size_t)jb * Dd);
        float acc = 0.f;
        #pragma unroll 8
        for (int kk = 0; kk < 64; ++kk) {
          const float4 e4 = ep[kk];
          const float* xp = &xs[w][kk * 4];
          acc = fmaf(xp[0], e4.x, acc);
          acc = fmaf(xp[1], e4.y, acc);
          acc = fmaf(xp[2], e4.z, acc);
          acc = fmaf(xp[3], e4.w, acc);
        }
        const float t1 = sxn + se[jb];
        scb = t1 - 2.0f * acc;
      }
    } else {
      // full exact scan: 16 codes per lane, ascending j per lane
      for (int jj = 0; jj < 16; ++jj) {
        const int j = lane * 16 + jj;
        const float4* ep = (const float4*)(emb + (size_t)j * Dd);
        float acc = 0.f;
        #pragma unroll 8
        for (int kk = 0; kk < 64; ++kk) {
          const float4 e4 = ep[kk];
          const float* xp = &xs[w][kk * 4];
          acc = fmaf(xp[0], e4.x, acc);
          acc = fmaf(xp[1], e4.y, acc);
          acc = fmaf(xp[2], e4.z, acc);
          acc = fmaf(xp[3], e4.w, acc);
        }
        const float t1 = sxn + se[j];
        const float sc = t1 - 2.0f * acc;
        if (sc < scb) { scb = sc; jb = j; }   // ascending j => strict < keeps first
      }
    }
    #pragma unroll
    for (int m = 1; m <= 32; m <<= 1) {
      const float so = __shfl_xor(scb, m, 64);
      const int jo = __shfl_xor(jb, m, 64);
      if (so < scb || (so == scb && jo < jb)) { scb = so; jb = jo; }
    }
    if (lane == 0) {
      idx_i[n] = jb;
      out_idx_f[n] = (float)jb;
      atomicAdd(&counts[jb], 1);
      wloss += (double)sxn + (double)scb;
    }
  }
  if (lane == 0) atomicAdd(loss_sum, wloss);
}

// gather-only z_q write (out == z_q; straight-through is identity in fwd)
__global__ __launch_bounds__(256) void phase2c_kernel(const float* __restrict__ emb,
                                                      const int* __restrict__ idx_i,
                                                      float* __restrict__ out_zq) {
  __shared__ float els[64 * 257];
  __shared__ int sidx[64];
  const int tid = threadIdx.x;
  const int blk = blockIdx.x, b = blk >> 8, s0 = (blk & 255) << 6;
  if (tid < 64) sidx[tid] = idx_i[b * SPATIAL + s0 + tid];
  __syncthreads();
  {
    const int rr = tid >> 2, p = tid & 3;
    const float* ep = emb + (size_t)sidx[rr] * Dd + p * 64;
    float* dl = els + rr * 257 + p * 64;
    #pragma unroll
    for (int i = 0; i < 64; i += 4) {
      const float4 e4 = *(const float4*)(ep + i);
      dl[i] = e4.x; dl[i + 1] = e4.y; dl[i + 2] = e4.z; dl[i + 3] = e4.w;
    }
  }
  __syncthreads();
  // vectorized store-out: lane covers 4 spatial positions -> float4 stores
  const int s4 = tid & 15, cg = tid >> 4;
  const size_t zb = (size_t)b * (Dd * SPATIAL);
  #pragma unroll 4
  for (int c = cg; c < Dd; c += 16) {
    float4 v;
    v.x = els[(s4 * 4 + 0) * 257 + c];
    v.y = els[(s4 * 4 + 1) * 257 + c];
    v.z = els[(s4 * 4 + 2) * 257 + c];
    v.w = els[(s4 * 4 + 3) * 257 + c];
    *(float4*)(out_zq + zb + (size_t)c * SPATIAL + s0 + s4 * 4) = v;
  }
}

__global__ __launch_bounds__(256) void finalize_kernel(const int* __restrict__ counts,
                                                       const double* __restrict__ loss_sum,
                                                       float* __restrict__ out) {
  const int tid = threadIdx.x;
  double local = 0.0;
  for (int k = tid; k < Kc; k += 256) {
    const double p = (double)counts[k] / (double)NROWS;
    local += p * log(p + 1e-10);
  }
  #pragma unroll
  for (int off = 32; off; off >>= 1) local += __shfl_down(local, off, 64);
  __shared__ double dred[4];
  if ((tid & 63) == 0) dred[tid >> 6] = local;
  __syncthreads();
  if (tid == 0) {
    const double H = dred[0] + dred[1] + dred[2] + dred[3];
    out[PERP_OFF] = (float)exp(-H);
    out[LOSS_OFF] = (float)(0.25 * loss_sum[0] / (double)NELEM);
  }
}

// ===================== OLD (round-3) FALLBACK PATH ==========================

__global__ __launch_bounds__(256) void prep_kernel(const float* __restrict__ emb,
                                                   float* __restrict__ eT,
                                                   float* __restrict__ se) {
  const int j = blockIdx.x, c = threadIdx.x;
  float v = emb[j * Dd + c];
  eT[c * Kc + j] = v;
  double s = (double)v * (double)v;
  #pragma unroll
  for (int off = 32; off; off >>= 1) s += __shfl_down(s, off, 64);
  __shared__ double ws4[4];
  if ((threadIdx.x & 63) == 0) ws4[threadIdx.x >> 6] = s;
  __syncthreads();
  if (threadIdx.x == 0) se[j] = (float)(ws4[0] + ws4[1] + ws4[2] + ws4[3]);
}

__global__ __launch_bounds__(256) void sx_kernel(const float* __restrict__ z,
                                                 float* __restrict__ sx) {
  __shared__ double part[4][64];
  const int tid = threadIdx.x, r = tid & 63, cg = tid >> 6;
  const int blk = blockIdx.x, b = blk >> 8, s0 = (blk & 255) << 6;
  const float* zb = z + (size_t)b * (Dd * SPATIAL);
  double acc = 0.0;
  for (int c = cg * 64; c < cg * 64 + 64; ++c) {
    const float v = zb[(size_t)c * SPATIAL + s0 + r];
    acc += (double)v * (double)v;
  }
  part[cg][r] = acc;
  __syncthreads();
  if (tid < 64)
    sx[b * SPATIAL + s0 + tid] =
        (float)(part[0][tid] + part[1][tid] + part[2][tid] + part[3][tid]);
}

__global__ __launch_bounds__(256) void argmin_kernel(const float* __restrict__ z,
                                                     const float* __restrict__ eT,
                                                     const float* __restrict__ se,
                                                     const float* __restrict__ sx,
                                                     float* __restrict__ out_idx_f,
                                                     int* __restrict__ idx_i,
                                                     int* __restrict__ counts) {
  __shared__ float As[32 * 64];
  __shared__ float Bs[32 * 64];
  __shared__ float ses[Kc];
  __shared__ float sxs[64];
  __shared__ float redS1[64 * 16];
  __shared__ int   redI1[64 * 16];
  const int tid = threadIdx.x, tc = tid & 15, tr = tid >> 4;
  const int blk = blockIdx.x, b = blk >> 8, s0 = (blk & 255) << 6;
  const float* zb = z + (size_t)b * (Dd * SPATIAL);
  #pragma unroll
  for (int i = 0; i < 4; ++i) ses[tid + 256 * i] = se[tid + 256 * i];
  if (tid < 64) sxs[tid] = sx[b * SPATIAL + s0 + tid];
  float s1[4]; int j1[4];
  #pragma unroll
  for (int r = 0; r < 4; ++r) { s1[r] = 3.4e38f; j1[r] = 0; }
  for (int j0 = 0; j0 < Kc; j0 += 64) {
    float acc[4][4];
    #pragma unroll
    for (int rr = 0; rr < 4; ++rr)
      #pragma unroll
      for (int cc = 0; cc < 4; ++cc) acc[rr][cc] = 0.0f;
    for (int c0 = 0; c0 < Dd; c0 += 32) {
      __syncthreads();
      #pragma unroll
      for (int i = 0; i < 8; ++i) {
        const int e = i * 256 + tid, ci = e >> 6, r = e & 63;
        As[e] = zb[(size_t)(c0 + ci) * SPATIAL + s0 + r];
        Bs[e] = eT[(c0 + ci) * Kc + j0 + r];
      }
      __syncthreads();
      #pragma unroll
      for (int d = 0; d < 32; ++d) {
        const float4 av = *reinterpret_cast<const float4*>(&As[d * 64 + 4 * tr]);
        const float4 bv = *reinterpret_cast<const float4*>(&Bs[d * 64 + 4 * tc]);
        const float aa[4] = {av.x, av.y, av.z, av.w};
        const float bb[4] = {bv.x, bv.y, bv.z, bv.w};
        #pragma unroll
        for (int rr = 0; rr < 4; ++rr)
          #pragma unroll
          for (int cc = 0; cc < 4; ++cc)
            acc[rr][cc] = fmaf(aa[rr], bb[cc], acc[rr][cc]);
      }
    }
    #pragma unroll
    for (int rr = 0; rr < 4; ++rr) {
      const float sxr = sxs[4 * tr + rr];
      #pragma unroll
      for (int cc = 0; cc < 4; ++cc) {
        const int j = j0 + 4 * tc + cc;
        const float t1 = sxr + ses[j];
        const float s = t1 - 2.0f * acc[rr][cc];
        if (s < s1[rr] || (s == s1[rr] && j < j1[rr])) { s1[rr] = s; j1[rr] = j; }
      }
    }
  }
  #pragma unroll
  for (int rr = 0; rr < 4; ++rr) {
    redS1[(4 * tr + rr) * 16 + tc] = s1[rr];
    redI1[(4 * tr + rr) * 16 + tc] = j1[rr];
  }
  __syncthreads();
  if (tid < 64) {
    float bs = redS1[tid * 16];
    int bj = redI1[tid * 16];
    #pragma unroll
    for (int t = 1; t < 16; ++t) {
      const float a1 = redS1[tid * 16 + t];
      const int aj = redI1[tid * 16 + t];
      if (a1 < bs || (a1 == bs && aj < bj)) { bs = a1; bj = aj; }
    }
    const int n = b * SPATIAL + s0 + tid;
    out_idx_f[n] = (float)bj;
    idx_i[n] = bj;
    atomicAdd(&counts[bj], 1);
  }
}

__global__ __launch_bounds__(256) void phase2_kernel(const float* __restrict__ z,
                                                     const float* __restrict__ eT,
                                                     const int* __restrict__ idx_i,
                                                     float* __restrict__ out_zq,
                                                     double* __restrict__ loss_sum) {
  __shared__ int sidx[64];
  __shared__ double dred[4];
  const int tid = threadIdx.x;
  const int blk = blockIdx.x, b = blk >> 8, s0 = (blk & 255) << 6;
  if (tid < 64) sidx[tid] = idx_i[b * SPATIAL + s0 + tid];
  __syncthreads();
  const int s = tid & 63, coff = tid >> 6;
  const size_t zb = (size_t)b * (Dd * SPATIAL);
  const int myidx = sidx[s];
  double lsum = 0.0;
  for (int c = coff; c < Dd; c += 4) {
    const size_t off = zb + (size_t)c * SPATIAL + s0 + s;
    const float zv = z[off];
    const float zq = eT[c * Kc + myidx];
    out_zq[off] = zv + (zq - zv);
    const float d = zv - zq;
    lsum += (double)d * (double)d;
  }
  #pragma unroll
  for (int off = 32; off; off >>= 1) lsum += __shfl_down(lsum, off, 64);
  if ((tid & 63) == 0) dred[tid >> 6] = lsum;
  __syncthreads();
  if (tid == 0) atomicAdd(loss_sum, dred[0] + dred[1] + dred[2] + dred[3]);
}

// ================================ LAUNCH ====================================

extern "C" void kernel_launch(void* const* d_in, const int* in_sizes, int n_in,
                              void* d_out, int out_size, void* d_ws, size_t ws_size,
                              hipStream_t stream) {
  const float* z   = (const float*)d_in[0];
  const float* emb = (const float*)d_in[1];
  float* out = (float*)d_out;
  char* ws = (char*)d_ws;

  // fast-path ws layout (rowmin slot retained but unused)
  const size_t OFF_SE   = 8192;
  const size_t OFF_SX   = 12288;
  const size_t OFF_EF   = 274432;
  const size_t OFF_RM   = 798720;
  const size_t OFF_IDX  = 1060864;
  const size_t OFF_CCT  = 1323008;
  const size_t OFF_CAND = 1585152;
  const size_t OFF_HARD = 3682304;
  const size_t NEED     = 3944448;
  (void)OFF_RM;

  double* loss_sum = (double*)(ws + 0);
  int*    hardcnt  = (int*)(ws + 8);
  int*    counts   = (int*)(ws + 256);

  hipMemsetAsync(d_ws, 0, 8192, stream);  // loss_sum + hardcnt + counts

  if (ws_size >= NEED) {
    float*    se        = (float*)(ws + OFF_SE);
    float*    sx        = (float*)(ws + OFF_SX);
    _Float16* efp       = (_Float16*)(ws + OFF_EF);
    int*      idx_i     = (int*)(ws + OFF_IDX);
    int*      candcount = (int*)(ws + OFF_CCT);
    int*      cand_g    = (int*)(ws + OFF_CAND);
    int*      hardlist  = (int*)(ws + OFF_HARD);

    prep2_kernel<<<Kc, 256, 0, stream>>>(emb, efp, se);
    prefilter2_kernel<<<2048, 512, 0, stream>>>(z, efp, se, sx, candcount, cand_g,
                                                out + IDX_OFF, idx_i, counts,
                                                hardcnt, hardlist, loss_sum);
    resolve_hard_kernel<<<256, 256, 0, stream>>>(z, emb, se, sx, candcount, cand_g,
                                                 hardcnt, hardlist, out + IDX_OFF,
                                                 idx_i, counts, loss_sum);
    phase2c_kernel<<<1024, 256, 0, stream>>>(emb, idx_i, out);
    finalize_kernel<<<1, 256, 0, stream>>>(counts, loss_sum, out);
  } else {
    // round-3 proven fallback
    float* eT    = (float*)(ws + 8192);
    float* se    = (float*)(ws + 8192 + 1048576);
    float* sx    = (float*)(ws + 8192 + 1048576 + 4096);
    int*   idx_i = (int*)(ws + 8192 + 1048576 + 4096 + 262144);

    prep_kernel<<<Kc, 256, 0, stream>>>(emb, eT, se);
    sx_kernel<<<1024, 256, 0, stream>>>(z, sx);
    argmin_kernel<<<1024, 256, 0, stream>>>(z, eT, se, sx, out + IDX_OFF, idx_i, counts);
    phase2_kernel<<<1024, 256, 0, stream>>>(z, eT, idx_i, out, loss_sum);
    finalize_kernel<<<1, 256, 0, stream>>>(counts, loss_sum, out);
  }
}